// Round 12
// baseline (242.813 us; speedup 1.0000x reference)
//
#include <hip/hip_runtime.h>

#define NP 64
#define DIM 512
#define NH 8
#define SCALE 0.125f

typedef __attribute__((ext_vector_type(4))) float f32x4;
typedef __attribute__((ext_vector_type(8))) short bf16x8;

// ---------------- workspace layout (bytes), high-water ~12.6 MB ----------------
#define WS_C   0                 // bf16 C[64][64] swizzled (8 KB)
#define WS_MT  8192              // bf16 Mt[4096][512] (4 MB) -> f32 Spart (4 MB)
#define WS_PT  4202496           // bf16 Pt[512 e][4096 K=(h,d)]    (4 MB)
#define WS_U   8396800           // bf16 U[256 b][4096 n=(h,e)]     (2 MB)
#define WS_Y   10493952          // bf16 Y[256 b][4096 K=(h,d)]     (2 MB)

static __device__ __forceinline__ unsigned short f2bf(float f) {
  unsigned int u = __builtin_bit_cast(unsigned int, f);
  u += 0x7fffu + ((u >> 16) & 1u);
  return (unsigned short)(u >> 16);
}
static __device__ __forceinline__ float bf2f(unsigned short s) {
  return __builtin_bit_cast(float, ((unsigned int)s) << 16);
}
static __device__ __forceinline__ unsigned pk2(float a, float b) {
  return (unsigned)f2bf(a) | ((unsigned)f2bf(b) << 16);
}

// ================= KW: batch-independent precompute =================
__global__ __launch_bounds__(512)
void kw_prep(const float* __restrict__ Wq, const float* __restrict__ Wkv,
             const float* __restrict__ Wout, const float* __restrict__ Wspec,
             char* __restrict__ ws) {
  __shared__ float wa[64 * 65];
  __shared__ float wb[64 * 65];
  const int t = threadIdx.x;
  const int blk = blockIdx.x;
  const int sr = t >> 3, sc8 = (t & 7) * 8;

  if (blk == 1024) {
    #pragma unroll
    for (int cc = 0; cc < 8; ++cc) {
      wa[sr * 65 + sc8 + cc] = Wspec[sr * 192 + sc8 + cc];
      wb[sr * 65 + sc8 + cc] = Wspec[sr * 192 + 64 + sc8 + cc];
    }
    __syncthreads();
    const int m = sr, mm0 = sc8;
    float acc[8] = {0.f, 0.f, 0.f, 0.f, 0.f, 0.f, 0.f, 0.f};
    for (int n = 0; n < 64; ++n) {
      float qv = wa[m * 65 + n];
      #pragma unroll
      for (int j = 0; j < 8; ++j)
        acc[j] = fmaf(qv, wb[(mm0 + j) * 65 + n], acc[j]);
    }
    uint4 pk;
    pk.x = pk2(acc[0] * SCALE, acc[1] * SCALE);
    pk.y = pk2(acc[2] * SCALE, acc[3] * SCALE);
    pk.z = pk2(acc[4] * SCALE, acc[5] * SCALE);
    pk.w = pk2(acc[6] * SCALE, acc[7] * SCALE);
    *(uint4*)(ws + WS_C + m * 128 + ((mm0 * 2) ^ ((m & 7) << 4))) = pk;
    return;
  }

  const bool isP = blk >= 512;
  const int id = blk & 511;
  const int h = id >> 6, et = (id >> 3) & 7, dt = id & 7;

  const float* sa = isP ? (Wkv + (size_t)(dt * 64 + sr) * 1024 + 512 + h * 64)
                        : (Wq + (size_t)(dt * 64 + sr) * 512 + h * 64);
  const float* sb = isP ? (Wout + (size_t)(h * 64 + sr) * 512 + et * 64)
                        : (Wkv + (size_t)(et * 64 + sr) * 1024 + h * 64);
  {
    float4 a0 = *(const float4*)(sa + sc8), a1 = *(const float4*)(sa + sc8 + 4);
    float* d = wa + sr * 65 + sc8;
    d[0] = a0.x; d[1] = a0.y; d[2] = a0.z; d[3] = a0.w;
    d[4] = a1.x; d[5] = a1.y; d[6] = a1.z; d[7] = a1.w;
    float4 b0 = *(const float4*)(sb + sc8), b1 = *(const float4*)(sb + sc8 + 4);
    float* e = wb + sr * 65 + sc8;
    e[0] = b0.x; e[1] = b0.y; e[2] = b0.z; e[3] = b0.w;
    e[4] = b1.x; e[5] = b1.y; e[6] = b1.z; e[7] = b1.w;
  }
  __syncthreads();

  const int er = sr, dc8 = sc8;
  float acc[8] = {0.f, 0.f, 0.f, 0.f, 0.f, 0.f, 0.f, 0.f};
  if (!isP) {
    for (int j = 0; j < 64; ++j) {
      float bv = wb[er * 65 + j];
      #pragma unroll
      for (int dd = 0; dd < 8; ++dd)
        acc[dd] = fmaf(bv, wa[(dc8 + dd) * 65 + j], acc[dd]);
    }
  } else {
    for (int j = 0; j < 64; ++j) {
      float bv = wb[j * 65 + er];
      #pragma unroll
      for (int dd = 0; dd < 8; ++dd)
        acc[dd] = fmaf(bv, wa[(dc8 + dd) * 65 + j], acc[dd]);
    }
  }
  uint4 pk;
  pk.x = pk2(acc[0], acc[1]);
  pk.y = pk2(acc[2], acc[3]);
  pk.z = pk2(acc[4], acc[5]);
  pk.w = pk2(acc[6], acc[7]);
  if (!isP)
    *(uint4*)(ws + WS_MT + ((size_t)(h * 512 + et * 64 + er) * 512 + dt * 64 + dc8) * 2) = pk;
  else
    *(uint4*)(ws + WS_PT + ((size_t)(et * 64 + er) * 4096 + h * 512 + dt * 64 + dc8) * 2) = pk;
}

// ================= KU: U[256][4096] = XC[256][512] @ Mt^T (bf16 MFMA) =================
#define GEMM_LDS 131072
__global__ __launch_bounds__(512, 2)
void ku_u(const float* __restrict__ x, const char* __restrict__ ws,
          char* __restrict__ ws_u) {
  extern __shared__ char sm[];
  char* At = sm;
  char* Bt = sm + 65536;
  const int t = threadIdx.x, lane = t & 63, wave = t >> 6;
  const int bt = blockIdx.x >> 6, nt = blockIdx.x & 63;
  const int b0 = bt * 64, n0 = nt * 64;
  const char* Mt = ws + WS_MT;

  #pragma unroll
  for (int i = 0; i < 8; ++i) {
    const int r = wave * 8 + i;
    const float4* xr = (const float4*)(x + ((size_t)(b0 + r) * 64 + 32) * 512);
    float4 a = xr[lane], c = xr[64 + lane];
    uint2 pa = {pk2(a.x, a.y), pk2(a.z, a.w)};
    uint2 pc = {pk2(c.x, c.y), pk2(c.z, c.w)};
    const int swz = (r & 7) << 4;
    const int byt = (8 * (lane & 15)) ^ swz;
    *(uint2*)(At + (lane >> 4) * 8192 + r * 128 + byt) = pa;
    *(uint2*)(At + (4 + (lane >> 4)) * 8192 + r * 128 + byt) = pc;
  }
  #pragma unroll
  for (int i = 0; i < 8; ++i) {
    const int r = wave * 8 + i;
    uint4 v = ((const uint4*)(Mt + (size_t)(n0 + r) * 1024))[lane];
    *(uint4*)(Bt + (lane >> 3) * 8192 + r * 128 + ((16 * (lane & 7)) ^ ((r & 7) << 4))) = v;
  }
  __syncthreads();

  const int lo = ((lane & 15) * 128) + (((lane >> 4) * 16) ^ ((lane & 7) << 4));
  const int hi = ((lane & 15) * 128) + ((((lane >> 4) * 16) + 64) ^ ((lane & 7) << 4));
  const int bsub = wave & 3, npair = wave >> 2;

  f32x4 c0 = {0.f, 0.f, 0.f, 0.f}, c1 = {0.f, 0.f, 0.f, 0.f};
  #pragma unroll
  for (int kc = 0; kc < 8; ++kc) {
    const char* ab = At + kc * 8192 + bsub * 2048;
    bf16x8 aL = *(const bf16x8*)(ab + lo);
    bf16x8 aH = *(const bf16x8*)(ab + hi);
    const char* bb0 = Bt + kc * 8192 + (npair * 2) * 2048;
    const char* bb1 = bb0 + 2048;
    c0 = __builtin_amdgcn_mfma_f32_16x16x32_bf16(aL, *(const bf16x8*)(bb0 + lo), c0, 0, 0, 0);
    c0 = __builtin_amdgcn_mfma_f32_16x16x32_bf16(aH, *(const bf16x8*)(bb0 + hi), c0, 0, 0, 0);
    c1 = __builtin_amdgcn_mfma_f32_16x16x32_bf16(aL, *(const bf16x8*)(bb1 + lo), c1, 0, 0, 0);
    c1 = __builtin_amdgcn_mfma_f32_16x16x32_bf16(aH, *(const bf16x8*)(bb1 + hi), c1, 0, 0, 0);
  }
  unsigned short* U = (unsigned short*)ws_u;
  const int brow = b0 + bsub * 16 + (lane >> 4) * 4;
  const int nc0 = n0 + (npair * 2) * 16 + (lane & 15);
  #pragma unroll
  for (int r = 0; r < 4; ++r) {
    U[(size_t)(brow + r) * 4096 + nc0] = f2bf(c0[r]);
    U[(size_t)(brow + r) * 4096 + nc0 + 16] = f2bf(c1[r]);
  }
}

// ================= K2: batch-local spatial attention =================
__global__ __launch_bounds__(512)
void k2_attn(const float* __restrict__ x, const char* __restrict__ ws_u,
             char* __restrict__ ws_y) {
  __shared__ float ul[8 * 512];
  __shared__ float scoreL[8 * 64];
  __shared__ float pT[64 * 8];
  const int t = threadIdx.x;
  const int lane = t & 63;
  const int wave = t >> 6;
  const int b = blockIdx.x;
  const float* xb = x + (size_t)b * NP * DIM;

  {
    uint4 v = ((const uint4*)(ws_u + (size_t)b * 8192))[t];
    const unsigned short* pv = (const unsigned short*)&v;
    float* d = ul + t * 8;
    #pragma unroll
    for (int g = 0; g < 8; ++g) d[g] = bf2f(pv[g]);
  }
  __syncthreads();

  {
    float4 uf0[8], uf1[8];
    #pragma unroll
    for (int h = 0; h < 8; ++h) {
      uf0[h] = *(const float4*)(ul + h * 512 + 4 * lane);
      uf1[h] = *(const float4*)(ul + h * 512 + 256 + 4 * lane);
    }
    #pragma unroll 2
    for (int i = 0; i < 8; ++i) {
      const int m = wave * 8 + i;
      const float4* xr = (const float4*)(xb + (size_t)m * DIM);
      float4 xv0 = xr[lane];
      float4 xv1 = xr[64 + lane];
      #pragma unroll
      for (int h = 0; h < 8; ++h) {
        float p = xv0.x * uf0[h].x + xv0.y * uf0[h].y + xv0.z * uf0[h].z + xv0.w * uf0[h].w
                + xv1.x * uf1[h].x + xv1.y * uf1[h].y + xv1.z * uf1[h].z + xv1.w * uf1[h].w;
        p += __shfl_xor(p, 1);
        p += __shfl_xor(p, 2);
        p += __shfl_xor(p, 4);
        p += __shfl_xor(p, 8);
        p += __shfl_xor(p, 16);
        p += __shfl_xor(p, 32);
        if (lane == 0) scoreL[h * 64 + m] = p;
      }
    }
  }
  __syncthreads();

  {
    float sc = scoreL[wave * 64 + lane] * SCALE;
    float mx = sc;
    #pragma unroll
    for (int off = 32; off > 0; off >>= 1)
      mx = fmaxf(mx, __shfl_xor(mx, off));
    float ev = __expf(sc - mx);
    float sm = ev;
    #pragma unroll
    for (int off = 32; off > 0; off >>= 1)
      sm += __shfl_xor(sm, off);
    pT[lane * NH + wave] = ev / sm;
  }
  __syncthreads();

  {
    float acc[NH];
    #pragma unroll
    for (int h = 0; h < NH; ++h) acc[h] = 0.f;
    #pragma unroll 2
    for (int m = 0; m < NP; ++m) {
      float xv = xb[(size_t)m * DIM + t];
      const float4* pp = (const float4*)(pT + m * NH);
      float4 p0 = pp[0], p1 = pp[1];
      acc[0] = fmaf(p0.x, xv, acc[0]);
      acc[1] = fmaf(p0.y, xv, acc[1]);
      acc[2] = fmaf(p0.z, xv, acc[2]);
      acc[3] = fmaf(p0.w, xv, acc[3]);
      acc[4] = fmaf(p1.x, xv, acc[4]);
      acc[5] = fmaf(p1.y, xv, acc[5]);
      acc[6] = fmaf(p1.z, xv, acc[6]);
      acc[7] = fmaf(p1.w, xv, acc[7]);
    }
    unsigned short* Y = (unsigned short*)ws_y;
    #pragma unroll
    for (int h = 0; h < NH; ++h)
      Y[(size_t)b * 4096 + h * 512 + t] = f2bf(acc[h]);
  }
}

// ================= KS: S partials via K-split. grid 256 = bt(4) x et(8) x sl(8) =================
__global__ __launch_bounds__(512, 2)
void ks_s(const char* __restrict__ ws_y, const char* __restrict__ ws_pt,
          float* __restrict__ Spart) {
  extern __shared__ char sm[];
  char* At = sm;
  char* Bt = sm + 65536;
  const int t = threadIdx.x, lane = t & 63, wave = t >> 6;
  const int bt = blockIdx.x >> 6, et = (blockIdx.x >> 3) & 7, sl = blockIdx.x & 7;
  const int b0 = bt * 64, e0 = et * 64;
  const size_t kb2 = (size_t)sl * 1024;

  #pragma unroll
  for (int i = 0; i < 8; ++i) {
    const int r = wave * 8 + i;
    const int byt = (16 * (lane & 7)) ^ ((r & 7) << 4);
    uint4 va = ((const uint4*)(ws_y + (size_t)(b0 + r) * 8192 + kb2))[lane];
    *(uint4*)(At + (lane >> 3) * 8192 + r * 128 + byt) = va;
    uint4 vb = ((const uint4*)(ws_pt + (size_t)(e0 + r) * 8192 + kb2))[lane];
    *(uint4*)(Bt + (lane >> 3) * 8192 + r * 128 + byt) = vb;
  }
  __syncthreads();

  const int lo = ((lane & 15) * 128) + (((lane >> 4) * 16) ^ ((lane & 7) << 4));
  const int hi = ((lane & 15) * 128) + ((((lane >> 4) * 16) + 64) ^ ((lane & 7) << 4));
  const int bsub = wave & 3, epair = wave >> 2;

  f32x4 c0 = {0.f, 0.f, 0.f, 0.f}, c1 = {0.f, 0.f, 0.f, 0.f};
  #pragma unroll
  for (int kc = 0; kc < 8; ++kc) {
    const char* ab = At + kc * 8192 + bsub * 2048;
    bf16x8 aL = *(const bf16x8*)(ab + lo);
    bf16x8 aH = *(const bf16x8*)(ab + hi);
    const char* bb0 = Bt + kc * 8192 + (epair * 2) * 2048;
    const char* bb1 = bb0 + 2048;
    c0 = __builtin_amdgcn_mfma_f32_16x16x32_bf16(aL, *(const bf16x8*)(bb0 + lo), c0, 0, 0, 0);
    c0 = __builtin_amdgcn_mfma_f32_16x16x32_bf16(aH, *(const bf16x8*)(bb0 + hi), c0, 0, 0, 0);
    c1 = __builtin_amdgcn_mfma_f32_16x16x32_bf16(aL, *(const bf16x8*)(bb1 + lo), c1, 0, 0, 0);
    c1 = __builtin_amdgcn_mfma_f32_16x16x32_bf16(aH, *(const bf16x8*)(bb1 + hi), c1, 0, 0, 0);
  }
  const int brow = b0 + bsub * 16 + (lane >> 4) * 4;
  const int ec0 = e0 + (epair * 2) * 16 + (lane & 15);
  #pragma unroll
  for (int r = 0; r < 4; ++r) {
    Spart[((size_t)sl * 256 + brow + r) * 512 + ec0] = c0[r];
    Spart[((size_t)sl * 256 + brow + r) * 512 + ec0 + 16] = c1[r];
  }
}

// ================= K4: spectral phase — single-MFMA-pass softmax via e-split wave pairs =================
// __launch_bounds__(1024, 4): 4 waves/EU = 1 block/CU -> 128-VGPR budget (round 11 spilled
// because the default targeted 2 blocks/CU = 64 VGPRs; live state here is ~113).
// region0 [0,65536): xT (stage+W2) -> w2T (phase C) -> wpart f32[8][512]
// Cc [65536,73728) ; s_l [73728,75776) ; rsx [75776,77824) f32[2][16][16]
#define K4_LDS 77824
__global__ __launch_bounds__(1024, 4)
void k4_spec(const float* __restrict__ x, const char* __restrict__ Cws,
             const float* __restrict__ Spart, const float* __restrict__ bout,
             float* __restrict__ out) {
  extern __shared__ char smem[];
  char* region0 = smem;
  char* Cc = smem + 65536;
  float* s_l = (float*)(smem + 73728);
  float* rsx = (float*)(smem + 75776);  // [2][16][16]

  const int t = threadIdx.x;
  const int lane = t & 63;
  const int wave = t >> 6;  // 0..15
  const int b = blockIdx.x;
  const float* xb = x + (size_t)b * NP * DIM;

  const int lo_off = ((lane & 15) * 128) + ((((lane >> 4) * 16)) ^ ((lane & 7) << 4));
  const int hi_off = ((lane & 15) * 128) + ((((lane >> 4) * 16) + 64) ^ ((lane & 7) << 4));

  // ---- stage xT (bf16, swizzled): thread halves split the 8 m-column groups ----
  {
    const int d = t & 511;
    const int cbase = (t >> 9) * 4;  // 0 or 4
    #pragma unroll
    for (int ci = 0; ci < 4; ++ci) {
      const int c = cbase + ci;
      float v0 = xb[(c * 8 + 0) * DIM + d];
      float v1 = xb[(c * 8 + 1) * DIM + d];
      float v2 = xb[(c * 8 + 2) * DIM + d];
      float v3 = xb[(c * 8 + 3) * DIM + d];
      float v4 = xb[(c * 8 + 4) * DIM + d];
      float v5 = xb[(c * 8 + 5) * DIM + d];
      float v6 = xb[(c * 8 + 6) * DIM + d];
      float v7 = xb[(c * 8 + 7) * DIM + d];
      uint4 pk;
      pk.x = pk2(v0, v1);
      pk.y = pk2(v2, v3);
      pk.z = pk2(v4, v5);
      pk.w = pk2(v6, v7);
      *(uint4*)(region0 + d * 128 + ((c * 16) ^ ((d & 7) << 4))) = pk;
    }
    if (t < 512) {
      ((uint4*)Cc)[t] = ((const uint4*)Cws)[t];
      float sacc = bout[t];
      #pragma unroll
      for (int sl = 0; sl < 8; ++sl)
        sacc += Spart[((size_t)sl * 256 + b) * 512 + t];
      s_l[t] = sacc;
    }
  }
  __syncthreads();

  // ---- hoist phase-C A-fragments: wave pair (w, w^8) shares d-blocks (pass*8 + (w&7)) ----
  bf16x8 pa0[4], pa1[4];
  #pragma unroll
  for (int pass = 0; pass < 4; ++pass) {
    const int d0 = (pass * 8 + (wave & 7)) * 16;
    pa0[pass] = *(const bf16x8*)(region0 + d0 * 128 + lo_off);
    pa1[pass] = *(const bf16x8*)(region0 + d0 * 128 + hi_off);
  }

  // ---- W2-MFMA into packed registers (region0 still = xT); 2 e-tiles per wave ----
  uint2 pkW2[2][4];  // [etl][mt]
  {
    bf16x8 af0[4], af1[4];
    #pragma unroll
    for (int mt = 0; mt < 4; ++mt) {
      af0[mt] = *(const bf16x8*)(Cc + mt * 16 * 128 + lo_off);
      af1[mt] = *(const bf16x8*)(Cc + mt * 16 * 128 + hi_off);
    }
    #pragma unroll
    for (int etl = 0; etl < 2; ++etl) {
      const int e0 = (wave * 2 + etl) * 16;
      bf16x8 b0 = *(const bf16x8*)(region0 + e0 * 128 + lo_off);
      bf16x8 b1 = *(const bf16x8*)(region0 + e0 * 128 + hi_off);
      #pragma unroll
      for (int mt = 0; mt < 4; ++mt) {
        f32x4 c = {0.f, 0.f, 0.f, 0.f};
        c = __builtin_amdgcn_mfma_f32_16x16x32_bf16(af0[mt], b0, c, 0, 0, 0);
        c = __builtin_amdgcn_mfma_f32_16x16x32_bf16(af1[mt], b1, c, 0, 0, 0);
        pkW2[etl][mt].x = pk2(c[0], c[1]);
        pkW2[etl][mt].y = pk2(c[2], c[3]);
      }
    }
  }
  __syncthreads();  // all waves done reading xT

  // ---- write w2T (bf16, swizzled) into region0, overwriting xT ----
  {
    #pragma unroll
    for (int etl = 0; etl < 2; ++etl) {
      const int e = (wave * 2 + etl) * 16 + (lane & 15);
      #pragma unroll
      for (int mt = 0; mt < 4; ++mt) {
        const int mrow = mt * 16 + (lane >> 4) * 4;
        *(uint2*)(region0 + e * 128 + ((mrow * 2) ^ ((e & 7) << 4))) = pkW2[etl][mt];
      }
    }
  }
  __syncthreads();

  // ---- phase C: single MFMA pass; wave pair splits e-range; rs exchanged via LDS ----
  float treg[16];
  #pragma unroll
  for (int i = 0; i < 16; ++i) treg[i] = 0.f;
  const int etbase = (wave >> 3) * 16;  // 0 or 16
  const int rowg = (lane >> 4) * 4;

  #pragma unroll
  for (int pass = 0; pass < 4; ++pass) {
    const int d0 = (pass * 8 + (wave & 7)) * 16;
    bf16x8 a0 = pa0[pass];
    bf16x8 a1 = pa1[pass];

    float rs[4] = {0.f, 0.f, 0.f, 0.f};
    uint2 pex[16];
    #pragma unroll
    for (int i = 0; i < 16; ++i) {
      const int et = etbase + i;
      bf16x8 b0 = *(const bf16x8*)(region0 + et * 2048 + lo_off);
      bf16x8 b1 = *(const bf16x8*)(region0 + et * 2048 + hi_off);
      f32x4 c = {0.f, 0.f, 0.f, 0.f};
      c = __builtin_amdgcn_mfma_f32_16x16x32_bf16(a0, b0, c, 0, 0, 0);
      c = __builtin_amdgcn_mfma_f32_16x16x32_bf16(a1, b1, c, 0, 0, 0);
      uint2 p;
      p.x = pk2(__expf(c[0]), __expf(c[1]));
      p.y = pk2(__expf(c[2]), __expf(c[3]));
      pex[i] = p;
      // accumulate rs from the rounded values (weights normalize exactly)
      rs[0] += bf2f((unsigned short)(p.x & 0xffffu));
      rs[1] += bf2f((unsigned short)(p.x >> 16));
      rs[2] += bf2f((unsigned short)(p.y & 0xffffu));
      rs[3] += bf2f((unsigned short)(p.y >> 16));
    }
    #pragma unroll
    for (int r = 0; r < 4; ++r) {
      rs[r] += __shfl_xor(rs[r], 1);
      rs[r] += __shfl_xor(rs[r], 2);
      rs[r] += __shfl_xor(rs[r], 4);
      rs[r] += __shfl_xor(rs[r], 8);
    }
    const int pb = pass & 1;
    if ((lane & 15) == 0) {
      #pragma unroll
      for (int r = 0; r < 4; ++r)
        rsx[pb * 256 + wave * 16 + rowg + r] = rs[r];
    }
    __syncthreads();
    float coef[4];
    #pragma unroll
    for (int r = 0; r < 4; ++r) {
      const float rfull = rsx[pb * 256 + wave * 16 + rowg + r]
                        + rsx[pb * 256 + (wave ^ 8) * 16 + rowg + r];
      coef[r] = s_l[d0 + rowg + r] / rfull;
    }
    #pragma unroll
    for (int i = 0; i < 16; ++i) {
      uint2 p = pex[i];
      float tp = treg[i];
      tp = fmaf(coef[0], bf2f((unsigned short)(p.x & 0xffffu)), tp);
      tp = fmaf(coef[1], bf2f((unsigned short)(p.x >> 16)), tp);
      tp = fmaf(coef[2], bf2f((unsigned short)(p.y & 0xffffu)), tp);
      tp = fmaf(coef[3], bf2f((unsigned short)(p.y >> 16)), tp);
      treg[i] = tp;
    }
  }

  // ---- reduce: sum treg over the 4 row-groups within each wave ----
  #pragma unroll
  for (int i = 0; i < 16; ++i) {
    treg[i] += __shfl_xor(treg[i], 16);
    treg[i] += __shfl_xor(treg[i], 32);
  }
  float* wpart = (float*)region0;  // [8][512]; cols 0..255 from waves 0..7, 256..511 from 8..15
  if (lane < 16) {
    #pragma unroll
    for (int i = 0; i < 16; ++i)
      wpart[(wave & 7) * 512 + (wave >> 3) * 256 + i * 16 + lane] = treg[i];
  }
  __syncthreads();

  const int e = t & 511;
  float tf = 0.f;
  #pragma unroll
  for (int w = 0; w < 8; ++w) tf += wpart[w * 512 + e];

  const int n0 = (t >> 9) * 32;
  float* ob = out + (size_t)b * NP * DIM + e;
  #pragma unroll 4
  for (int n = n0; n < n0 + 32; ++n) ob[n * DIM] = tf;
}

extern "C" void kernel_launch(void* const* d_in, const int* in_sizes, int n_in,
                              void* d_out, int out_size, void* d_ws, size_t ws_size,
                              hipStream_t stream) {
  (void)in_sizes; (void)n_in; (void)out_size; (void)ws_size;
  const float* x     = (const float*)d_in[0];
  const float* Wq    = (const float*)d_in[1];
  const float* Wkv   = (const float*)d_in[2];
  const float* Wout  = (const float*)d_in[3];
  const float* bout  = (const float*)d_in[4];
  const float* Wspec = (const float*)d_in[5];
  float* out = (float*)d_out;

  char* ws = (char*)d_ws;

  hipFuncSetAttribute(reinterpret_cast<const void*>(ku_u),
                      hipFuncAttributeMaxDynamicSharedMemorySize, GEMM_LDS);
  hipFuncSetAttribute(reinterpret_cast<const void*>(ks_s),
                      hipFuncAttributeMaxDynamicSharedMemorySize, GEMM_LDS);
  hipFuncSetAttribute(reinterpret_cast<const void*>(k4_spec),
                      hipFuncAttributeMaxDynamicSharedMemorySize, K4_LDS);

  kw_prep<<<dim3(1025), dim3(512), 0, stream>>>(Wq, Wkv, Wout, Wspec, ws);
  ku_u   <<<dim3(256),  dim3(512), GEMM_LDS, stream>>>(x, ws, ws + WS_U);
  k2_attn<<<dim3(256),  dim3(512), 0, stream>>>(x, ws + WS_U, ws + WS_Y);
  ks_s   <<<dim3(256),  dim3(512), GEMM_LDS, stream>>>(ws + WS_Y, ws + WS_PT,
                                                       (float*)(ws + WS_MT));
  k4_spec<<<dim3(256),  dim3(1024), K4_LDS, stream>>>(x, ws, (const float*)(ws + WS_MT),
                                                      bout, out);
}

// Round 13
// 107.706 us; speedup vs baseline: 2.2544x; 2.2544x over previous
//
#include <hip/hip_runtime.h>

#define NP 64
#define DIM 512
#define NH 8
#define SCALE 0.125f

typedef __attribute__((ext_vector_type(4))) float f32x4;
typedef __attribute__((ext_vector_type(8))) short bf16x8;

// ---------------- workspace layout (bytes), high-water ~12.6 MB ----------------
#define WS_C   0                 // bf16 C[64][64] swizzled (8 KB)
#define WS_MT  8192              // bf16 Mt[4096][512] (4 MB) -> f32 Spart (4 MB)
#define WS_PT  4202496           // bf16 Pt[512 e][4096 K=(h,d)]    (4 MB)
#define WS_U   8396800           // bf16 U[256 b][4096 n=(h,e)]     (2 MB)
#define WS_Y   10493952          // bf16 Y[256 b][4096 K=(h,d)]     (2 MB)

static __device__ __forceinline__ unsigned short f2bf(float f) {
  unsigned int u = __builtin_bit_cast(unsigned int, f);
  u += 0x7fffu + ((u >> 16) & 1u);
  return (unsigned short)(u >> 16);
}
static __device__ __forceinline__ float bf2f(unsigned short s) {
  return __builtin_bit_cast(float, ((unsigned int)s) << 16);
}
static __device__ __forceinline__ unsigned pk2(float a, float b) {
  return (unsigned)f2bf(a) | ((unsigned)f2bf(b) << 16);
}

// ================= KW: batch-independent precompute =================
__global__ __launch_bounds__(512)
void kw_prep(const float* __restrict__ Wq, const float* __restrict__ Wkv,
             const float* __restrict__ Wout, const float* __restrict__ Wspec,
             char* __restrict__ ws) {
  __shared__ float wa[64 * 65];
  __shared__ float wb[64 * 65];
  const int t = threadIdx.x;
  const int blk = blockIdx.x;
  const int sr = t >> 3, sc8 = (t & 7) * 8;

  if (blk == 1024) {
    #pragma unroll
    for (int cc = 0; cc < 8; ++cc) {
      wa[sr * 65 + sc8 + cc] = Wspec[sr * 192 + sc8 + cc];
      wb[sr * 65 + sc8 + cc] = Wspec[sr * 192 + 64 + sc8 + cc];
    }
    __syncthreads();
    const int m = sr, mm0 = sc8;
    float acc[8] = {0.f, 0.f, 0.f, 0.f, 0.f, 0.f, 0.f, 0.f};
    for (int n = 0; n < 64; ++n) {
      float qv = wa[m * 65 + n];
      #pragma unroll
      for (int j = 0; j < 8; ++j)
        acc[j] = fmaf(qv, wb[(mm0 + j) * 65 + n], acc[j]);
    }
    uint4 pk;
    pk.x = pk2(acc[0] * SCALE, acc[1] * SCALE);
    pk.y = pk2(acc[2] * SCALE, acc[3] * SCALE);
    pk.z = pk2(acc[4] * SCALE, acc[5] * SCALE);
    pk.w = pk2(acc[6] * SCALE, acc[7] * SCALE);
    *(uint4*)(ws + WS_C + m * 128 + ((mm0 * 2) ^ ((m & 7) << 4))) = pk;
    return;
  }

  const bool isP = blk >= 512;
  const int id = blk & 511;
  const int h = id >> 6, et = (id >> 3) & 7, dt = id & 7;

  const float* sa = isP ? (Wkv + (size_t)(dt * 64 + sr) * 1024 + 512 + h * 64)
                        : (Wq + (size_t)(dt * 64 + sr) * 512 + h * 64);
  const float* sb = isP ? (Wout + (size_t)(h * 64 + sr) * 512 + et * 64)
                        : (Wkv + (size_t)(et * 64 + sr) * 1024 + h * 64);
  {
    float4 a0 = *(const float4*)(sa + sc8), a1 = *(const float4*)(sa + sc8 + 4);
    float* d = wa + sr * 65 + sc8;
    d[0] = a0.x; d[1] = a0.y; d[2] = a0.z; d[3] = a0.w;
    d[4] = a1.x; d[5] = a1.y; d[6] = a1.z; d[7] = a1.w;
    float4 b0 = *(const float4*)(sb + sc8), b1 = *(const float4*)(sb + sc8 + 4);
    float* e = wb + sr * 65 + sc8;
    e[0] = b0.x; e[1] = b0.y; e[2] = b0.z; e[3] = b0.w;
    e[4] = b1.x; e[5] = b1.y; e[6] = b1.z; e[7] = b1.w;
  }
  __syncthreads();

  const int er = sr, dc8 = sc8;
  float acc[8] = {0.f, 0.f, 0.f, 0.f, 0.f, 0.f, 0.f, 0.f};
  if (!isP) {
    for (int j = 0; j < 64; ++j) {
      float bv = wb[er * 65 + j];
      #pragma unroll
      for (int dd = 0; dd < 8; ++dd)
        acc[dd] = fmaf(bv, wa[(dc8 + dd) * 65 + j], acc[dd]);
    }
  } else {
    for (int j = 0; j < 64; ++j) {
      float bv = wb[j * 65 + er];
      #pragma unroll
      for (int dd = 0; dd < 8; ++dd)
        acc[dd] = fmaf(bv, wa[(dc8 + dd) * 65 + j], acc[dd]);
    }
  }
  uint4 pk;
  pk.x = pk2(acc[0], acc[1]);
  pk.y = pk2(acc[2], acc[3]);
  pk.z = pk2(acc[4], acc[5]);
  pk.w = pk2(acc[6], acc[7]);
  if (!isP)
    *(uint4*)(ws + WS_MT + ((size_t)(h * 512 + et * 64 + er) * 512 + dt * 64 + dc8) * 2) = pk;
  else
    *(uint4*)(ws + WS_PT + ((size_t)(et * 64 + er) * 4096 + h * 512 + dt * 64 + dc8) * 2) = pk;
}

// ================= KU: U[256][4096] = XC[256][512] @ Mt^T (bf16 MFMA) =================
#define GEMM_LDS 131072
__global__ __launch_bounds__(512, 2)
void ku_u(const float* __restrict__ x, const char* __restrict__ ws,
          char* __restrict__ ws_u) {
  extern __shared__ char sm[];
  char* At = sm;
  char* Bt = sm + 65536;
  const int t = threadIdx.x, lane = t & 63, wave = t >> 6;
  const int bt = blockIdx.x >> 6, nt = blockIdx.x & 63;
  const int b0 = bt * 64, n0 = nt * 64;
  const char* Mt = ws + WS_MT;

  #pragma unroll
  for (int i = 0; i < 8; ++i) {
    const int r = wave * 8 + i;
    const float4* xr = (const float4*)(x + ((size_t)(b0 + r) * 64 + 32) * 512);
    float4 a = xr[lane], c = xr[64 + lane];
    uint2 pa = {pk2(a.x, a.y), pk2(a.z, a.w)};
    uint2 pc = {pk2(c.x, c.y), pk2(c.z, c.w)};
    const int swz = (r & 7) << 4;
    const int byt = (8 * (lane & 15)) ^ swz;
    *(uint2*)(At + (lane >> 4) * 8192 + r * 128 + byt) = pa;
    *(uint2*)(At + (4 + (lane >> 4)) * 8192 + r * 128 + byt) = pc;
  }
  #pragma unroll
  for (int i = 0; i < 8; ++i) {
    const int r = wave * 8 + i;
    uint4 v = ((const uint4*)(Mt + (size_t)(n0 + r) * 1024))[lane];
    *(uint4*)(Bt + (lane >> 3) * 8192 + r * 128 + ((16 * (lane & 7)) ^ ((r & 7) << 4))) = v;
  }
  __syncthreads();

  const int lo = ((lane & 15) * 128) + (((lane >> 4) * 16) ^ ((lane & 7) << 4));
  const int hi = ((lane & 15) * 128) + ((((lane >> 4) * 16) + 64) ^ ((lane & 7) << 4));
  const int bsub = wave & 3, npair = wave >> 2;

  f32x4 c0 = {0.f, 0.f, 0.f, 0.f}, c1 = {0.f, 0.f, 0.f, 0.f};
  #pragma unroll
  for (int kc = 0; kc < 8; ++kc) {
    const char* ab = At + kc * 8192 + bsub * 2048;
    bf16x8 aL = *(const bf16x8*)(ab + lo);
    bf16x8 aH = *(const bf16x8*)(ab + hi);
    const char* bb0 = Bt + kc * 8192 + (npair * 2) * 2048;
    const char* bb1 = bb0 + 2048;
    c0 = __builtin_amdgcn_mfma_f32_16x16x32_bf16(aL, *(const bf16x8*)(bb0 + lo), c0, 0, 0, 0);
    c0 = __builtin_amdgcn_mfma_f32_16x16x32_bf16(aH, *(const bf16x8*)(bb0 + hi), c0, 0, 0, 0);
    c1 = __builtin_amdgcn_mfma_f32_16x16x32_bf16(aL, *(const bf16x8*)(bb1 + lo), c1, 0, 0, 0);
    c1 = __builtin_amdgcn_mfma_f32_16x16x32_bf16(aH, *(const bf16x8*)(bb1 + hi), c1, 0, 0, 0);
  }
  unsigned short* U = (unsigned short*)ws_u;
  const int brow = b0 + bsub * 16 + (lane >> 4) * 4;
  const int nc0 = n0 + (npair * 2) * 16 + (lane & 15);
  #pragma unroll
  for (int r = 0; r < 4; ++r) {
    U[(size_t)(brow + r) * 4096 + nc0] = f2bf(c0[r]);
    U[(size_t)(brow + r) * 4096 + nc0 + 16] = f2bf(c1[r]);
  }
}

// ================= K2: batch-local spatial attention =================
__global__ __launch_bounds__(512)
void k2_attn(const float* __restrict__ x, const char* __restrict__ ws_u,
             char* __restrict__ ws_y) {
  __shared__ float ul[8 * 512];
  __shared__ float scoreL[8 * 64];
  __shared__ float pT[64 * 8];
  const int t = threadIdx.x;
  const int lane = t & 63;
  const int wave = t >> 6;
  const int b = blockIdx.x;
  const float* xb = x + (size_t)b * NP * DIM;

  {
    uint4 v = ((const uint4*)(ws_u + (size_t)b * 8192))[t];
    const unsigned short* pv = (const unsigned short*)&v;
    float* d = ul + t * 8;
    #pragma unroll
    for (int g = 0; g < 8; ++g) d[g] = bf2f(pv[g]);
  }
  __syncthreads();

  {
    float4 uf0[8], uf1[8];
    #pragma unroll
    for (int h = 0; h < 8; ++h) {
      uf0[h] = *(const float4*)(ul + h * 512 + 4 * lane);
      uf1[h] = *(const float4*)(ul + h * 512 + 256 + 4 * lane);
    }
    #pragma unroll 2
    for (int i = 0; i < 8; ++i) {
      const int m = wave * 8 + i;
      const float4* xr = (const float4*)(xb + (size_t)m * DIM);
      float4 xv0 = xr[lane];
      float4 xv1 = xr[64 + lane];
      #pragma unroll
      for (int h = 0; h < 8; ++h) {
        float p = xv0.x * uf0[h].x + xv0.y * uf0[h].y + xv0.z * uf0[h].z + xv0.w * uf0[h].w
                + xv1.x * uf1[h].x + xv1.y * uf1[h].y + xv1.z * uf1[h].z + xv1.w * uf1[h].w;
        p += __shfl_xor(p, 1);
        p += __shfl_xor(p, 2);
        p += __shfl_xor(p, 4);
        p += __shfl_xor(p, 8);
        p += __shfl_xor(p, 16);
        p += __shfl_xor(p, 32);
        if (lane == 0) scoreL[h * 64 + m] = p;
      }
    }
  }
  __syncthreads();

  {
    float sc = scoreL[wave * 64 + lane] * SCALE;
    float mx = sc;
    #pragma unroll
    for (int off = 32; off > 0; off >>= 1)
      mx = fmaxf(mx, __shfl_xor(mx, off));
    float ev = __expf(sc - mx);
    float sm = ev;
    #pragma unroll
    for (int off = 32; off > 0; off >>= 1)
      sm += __shfl_xor(sm, off);
    pT[lane * NH + wave] = ev / sm;
  }
  __syncthreads();

  {
    float acc[NH];
    #pragma unroll
    for (int h = 0; h < NH; ++h) acc[h] = 0.f;
    #pragma unroll 2
    for (int m = 0; m < NP; ++m) {
      float xv = xb[(size_t)m * DIM + t];
      const float4* pp = (const float4*)(pT + m * NH);
      float4 p0 = pp[0], p1 = pp[1];
      acc[0] = fmaf(p0.x, xv, acc[0]);
      acc[1] = fmaf(p0.y, xv, acc[1]);
      acc[2] = fmaf(p0.z, xv, acc[2]);
      acc[3] = fmaf(p0.w, xv, acc[3]);
      acc[4] = fmaf(p1.x, xv, acc[4]);
      acc[5] = fmaf(p1.y, xv, acc[5]);
      acc[6] = fmaf(p1.z, xv, acc[6]);
      acc[7] = fmaf(p1.w, xv, acc[7]);
    }
    unsigned short* Y = (unsigned short*)ws_y;
    #pragma unroll
    for (int h = 0; h < NH; ++h)
      Y[(size_t)b * 4096 + h * 512 + t] = f2bf(acc[h]);
  }
}

// ================= KS: S partials via K-split. grid 256 = bt(4) x et(8) x sl(8) =================
__global__ __launch_bounds__(512, 2)
void ks_s(const char* __restrict__ ws_y, const char* __restrict__ ws_pt,
          float* __restrict__ Spart) {
  extern __shared__ char sm[];
  char* At = sm;
  char* Bt = sm + 65536;
  const int t = threadIdx.x, lane = t & 63, wave = t >> 6;
  const int bt = blockIdx.x >> 6, et = (blockIdx.x >> 3) & 7, sl = blockIdx.x & 7;
  const int b0 = bt * 64, e0 = et * 64;
  const size_t kb2 = (size_t)sl * 1024;

  #pragma unroll
  for (int i = 0; i < 8; ++i) {
    const int r = wave * 8 + i;
    const int byt = (16 * (lane & 7)) ^ ((r & 7) << 4);
    uint4 va = ((const uint4*)(ws_y + (size_t)(b0 + r) * 8192 + kb2))[lane];
    *(uint4*)(At + (lane >> 3) * 8192 + r * 128 + byt) = va;
    uint4 vb = ((const uint4*)(ws_pt + (size_t)(e0 + r) * 8192 + kb2))[lane];
    *(uint4*)(Bt + (lane >> 3) * 8192 + r * 128 + byt) = vb;
  }
  __syncthreads();

  const int lo = ((lane & 15) * 128) + (((lane >> 4) * 16) ^ ((lane & 7) << 4));
  const int hi = ((lane & 15) * 128) + ((((lane >> 4) * 16) + 64) ^ ((lane & 7) << 4));
  const int bsub = wave & 3, epair = wave >> 2;

  f32x4 c0 = {0.f, 0.f, 0.f, 0.f}, c1 = {0.f, 0.f, 0.f, 0.f};
  #pragma unroll
  for (int kc = 0; kc < 8; ++kc) {
    const char* ab = At + kc * 8192 + bsub * 2048;
    bf16x8 aL = *(const bf16x8*)(ab + lo);
    bf16x8 aH = *(const bf16x8*)(ab + hi);
    const char* bb0 = Bt + kc * 8192 + (epair * 2) * 2048;
    const char* bb1 = bb0 + 2048;
    c0 = __builtin_amdgcn_mfma_f32_16x16x32_bf16(aL, *(const bf16x8*)(bb0 + lo), c0, 0, 0, 0);
    c0 = __builtin_amdgcn_mfma_f32_16x16x32_bf16(aH, *(const bf16x8*)(bb0 + hi), c0, 0, 0, 0);
    c1 = __builtin_amdgcn_mfma_f32_16x16x32_bf16(aL, *(const bf16x8*)(bb1 + lo), c1, 0, 0, 0);
    c1 = __builtin_amdgcn_mfma_f32_16x16x32_bf16(aH, *(const bf16x8*)(bb1 + hi), c1, 0, 0, 0);
  }
  const int brow = b0 + bsub * 16 + (lane >> 4) * 4;
  const int ec0 = e0 + (epair * 2) * 16 + (lane & 15);
  #pragma unroll
  for (int r = 0; r < 4; ++r) {
    Spart[((size_t)sl * 256 + brow + r) * 512 + ec0] = c0[r];
    Spart[((size_t)sl * 256 + brow + r) * 512 + ec0 + 16] = c1[r];
  }
}

// ================= K4: e-split single-MFMA-pass softmax, 512 threads, xT resident =================
// LDS: xT [0,64K) ; w2T [64K,128K) ; Cc [128K,136K) ; s_l [136K+3K=139264..141312) ; rsx [141312,142336)
// 8 waves = 4 d-slots x 2 e-halves; 8 passes; rs exchanged via double-buffered rsx (1 barrier/pass).
// 512-thread block => 128-VGPR budget (observed r3-r9); phase-C live ~90 regs => no spill.
#define K4_LDS 142336
__global__ __launch_bounds__(512)
void k4_spec(const float* __restrict__ x, const char* __restrict__ Cws,
             const float* __restrict__ Spart, const float* __restrict__ bout,
             float* __restrict__ out) {
  extern __shared__ char smem[];
  char* xTc  = smem;
  char* w2Tc = smem + 65536;
  char* Cc   = smem + 131072;
  float* s_l = (float*)(smem + 139264);
  float* rsx = (float*)(smem + 141312);  // [2][8][16]

  const int t = threadIdx.x;
  const int lane = t & 63;
  const int wave = t >> 6;  // 0..7
  const int b = blockIdx.x;
  const float* xb = x + (size_t)b * NP * DIM;

  const int lo_off = ((lane & 15) * 128) + ((((lane >> 4) * 16)) ^ ((lane & 7) << 4));
  const int hi_off = ((lane & 15) * 128) + ((((lane >> 4) * 16) + 64) ^ ((lane & 7) << 4));

  // ---- stage xT (bf16, swizzled), C, s_l ----
  {
    const int d = t;
    #pragma unroll
    for (int c = 0; c < 8; ++c) {
      float v0 = xb[(c * 8 + 0) * DIM + d];
      float v1 = xb[(c * 8 + 1) * DIM + d];
      float v2 = xb[(c * 8 + 2) * DIM + d];
      float v3 = xb[(c * 8 + 3) * DIM + d];
      float v4 = xb[(c * 8 + 4) * DIM + d];
      float v5 = xb[(c * 8 + 5) * DIM + d];
      float v6 = xb[(c * 8 + 6) * DIM + d];
      float v7 = xb[(c * 8 + 7) * DIM + d];
      uint4 pk;
      pk.x = pk2(v0, v1);
      pk.y = pk2(v2, v3);
      pk.z = pk2(v4, v5);
      pk.w = pk2(v6, v7);
      *(uint4*)(xTc + d * 128 + ((c * 16) ^ ((d & 7) << 4))) = pk;
    }
    ((uint4*)Cc)[t] = ((const uint4*)Cws)[t];
    float sacc = bout[t];
    #pragma unroll
    for (int sl = 0; sl < 8; ++sl)
      sacc += Spart[((size_t)sl * 256 + b) * 512 + t];
    s_l[t] = sacc;
  }
  __syncthreads();

  // ---- W2-MFMA: read xT (region0), write w2T DIRECTLY (distinct region, no staging regs) ----
  {
    bf16x8 af0[4], af1[4];
    #pragma unroll
    for (int mt = 0; mt < 4; ++mt) {
      af0[mt] = *(const bf16x8*)(Cc + mt * 16 * 128 + lo_off);
      af1[mt] = *(const bf16x8*)(Cc + mt * 16 * 128 + hi_off);
    }
    #pragma unroll
    for (int etl = 0; etl < 4; ++etl) {
      const int e0 = (wave * 4 + etl) * 16;
      bf16x8 b0 = *(const bf16x8*)(xTc + e0 * 128 + lo_off);
      bf16x8 b1 = *(const bf16x8*)(xTc + e0 * 128 + hi_off);
      const int e = e0 + (lane & 15);
      #pragma unroll
      for (int mt = 0; mt < 4; ++mt) {
        f32x4 c = {0.f, 0.f, 0.f, 0.f};
        c = __builtin_amdgcn_mfma_f32_16x16x32_bf16(af0[mt], b0, c, 0, 0, 0);
        c = __builtin_amdgcn_mfma_f32_16x16x32_bf16(af1[mt], b1, c, 0, 0, 0);
        const int mrow = mt * 16 + (lane >> 4) * 4;
        uint2 pk;
        pk.x = pk2(c[0], c[1]);
        pk.y = pk2(c[2], c[3]);
        *(uint2*)(w2Tc + e * 128 + ((mrow * 2) ^ ((e & 7) << 4))) = pk;
      }
    }
  }
  __syncthreads();

  // ---- phase C: 8 passes; wave = (dslot, ehalf); single MFMA pass, pex kept packed ----
  const int dslot = wave & 3, ehalf = wave >> 2;
  const int rowg = (lane >> 4) * 4;
  float treg[16];
  #pragma unroll
  for (int i = 0; i < 16; ++i) treg[i] = 0.f;

  #pragma unroll 1
  for (int pass = 0; pass < 8; ++pass) {
    const int d0 = (pass * 4 + dslot) * 16;
    bf16x8 a0 = *(const bf16x8*)(xTc + d0 * 128 + lo_off);
    bf16x8 a1 = *(const bf16x8*)(xTc + d0 * 128 + hi_off);

    float rs[4] = {0.f, 0.f, 0.f, 0.f};
    uint2 pex[16];
    #pragma unroll
    for (int i = 0; i < 16; ++i) {
      const int et = ehalf * 16 + i;
      bf16x8 b0 = *(const bf16x8*)(w2Tc + et * 2048 + lo_off);
      bf16x8 b1 = *(const bf16x8*)(w2Tc + et * 2048 + hi_off);
      f32x4 c = {0.f, 0.f, 0.f, 0.f};
      c = __builtin_amdgcn_mfma_f32_16x16x32_bf16(a0, b0, c, 0, 0, 0);
      c = __builtin_amdgcn_mfma_f32_16x16x32_bf16(a1, b1, c, 0, 0, 0);
      uint2 p;
      p.x = pk2(__expf(c[0]), __expf(c[1]));
      p.y = pk2(__expf(c[2]), __expf(c[3]));
      pex[i] = p;
      rs[0] += bf2f((unsigned short)(p.x & 0xffffu));
      rs[1] += bf2f((unsigned short)(p.x >> 16));
      rs[2] += bf2f((unsigned short)(p.y & 0xffffu));
      rs[3] += bf2f((unsigned short)(p.y >> 16));
    }
    #pragma unroll
    for (int r = 0; r < 4; ++r) {
      rs[r] += __shfl_xor(rs[r], 1);
      rs[r] += __shfl_xor(rs[r], 2);
      rs[r] += __shfl_xor(rs[r], 4);
      rs[r] += __shfl_xor(rs[r], 8);
    }
    const int pb = pass & 1;
    if ((lane & 15) == 0) {
      #pragma unroll
      for (int r = 0; r < 4; ++r)
        rsx[pb * 128 + wave * 16 + rowg + r] = rs[r];
    }
    __syncthreads();
    float coef[4];
    #pragma unroll
    for (int r = 0; r < 4; ++r) {
      const float rfull = rsx[pb * 128 + wave * 16 + rowg + r]
                        + rsx[pb * 128 + (wave ^ 4) * 16 + rowg + r];
      coef[r] = s_l[d0 + rowg + r] / rfull;
    }
    #pragma unroll
    for (int i = 0; i < 16; ++i) {
      uint2 p = pex[i];
      float tp = treg[i];
      tp = fmaf(coef[0], bf2f((unsigned short)(p.x & 0xffffu)), tp);
      tp = fmaf(coef[1], bf2f((unsigned short)(p.x >> 16)), tp);
      tp = fmaf(coef[2], bf2f((unsigned short)(p.y & 0xffffu)), tp);
      tp = fmaf(coef[3], bf2f((unsigned short)(p.y >> 16)), tp);
      treg[i] = tp;
    }
  }

  // ---- reduce over the 4 row-groups within each wave ----
  #pragma unroll
  for (int i = 0; i < 16; ++i) {
    treg[i] += __shfl_xor(treg[i], 16);
    treg[i] += __shfl_xor(treg[i], 32);
  }
  // all xT/w2T reads precede the final pass's barrier for every wave -> safe to overwrite xT
  float* wpart = (float*)xTc;  // [4][512]; per dslot partials
  if (lane < 16) {
    #pragma unroll
    for (int i = 0; i < 16; ++i)
      wpart[dslot * 512 + ehalf * 256 + i * 16 + lane] = treg[i];
  }
  __syncthreads();

  float tf = 0.f;
  #pragma unroll
  for (int w = 0; w < 4; ++w) tf += wpart[w * 512 + t];

  float* ob = out + (size_t)b * NP * DIM + t;
  #pragma unroll 4
  for (int n = 0; n < NP; ++n) ob[n * DIM] = tf;
}

extern "C" void kernel_launch(void* const* d_in, const int* in_sizes, int n_in,
                              void* d_out, int out_size, void* d_ws, size_t ws_size,
                              hipStream_t stream) {
  (void)in_sizes; (void)n_in; (void)out_size; (void)ws_size;
  const float* x     = (const float*)d_in[0];
  const float* Wq    = (const float*)d_in[1];
  const float* Wkv   = (const float*)d_in[2];
  const float* Wout  = (const float*)d_in[3];
  const float* bout  = (const float*)d_in[4];
  const float* Wspec = (const float*)d_in[5];
  float* out = (float*)d_out;

  char* ws = (char*)d_ws;

  hipFuncSetAttribute(reinterpret_cast<const void*>(ku_u),
                      hipFuncAttributeMaxDynamicSharedMemorySize, GEMM_LDS);
  hipFuncSetAttribute(reinterpret_cast<const void*>(ks_s),
                      hipFuncAttributeMaxDynamicSharedMemorySize, GEMM_LDS);
  hipFuncSetAttribute(reinterpret_cast<const void*>(k4_spec),
                      hipFuncAttributeMaxDynamicSharedMemorySize, K4_LDS);

  kw_prep<<<dim3(1025), dim3(512), 0, stream>>>(Wq, Wkv, Wout, Wspec, ws);
  ku_u   <<<dim3(256),  dim3(512), GEMM_LDS, stream>>>(x, ws, ws + WS_U);
  k2_attn<<<dim3(256),  dim3(512), 0, stream>>>(x, ws + WS_U, ws + WS_Y);
  ks_s   <<<dim3(256),  dim3(512), GEMM_LDS, stream>>>(ws + WS_Y, ws + WS_PT,
                                                       (float*)(ws + WS_MT));
  k4_spec<<<dim3(256),  dim3(512), K4_LDS, stream>>>(x, ws, (const float*)(ws + WS_MT),
                                                     bout, out);
}